// Round 7
// baseline (296.895 us; speedup 1.0000x reference)
//
#include <hip/hip_runtime.h>

#define INPUT_DIM 16
#define COLS 273                                   // 1 + 16 + 256
#define ROWS_PER_TILE 16
#define FLOATS_PER_TILE (ROWS_PER_TILE * COLS)     // 4368
#define VEC4_PER_TILE (FLOATS_PER_TILE / 4)        // 1092
#define NBLOCKS 2048                               // 8 resident/CU (LDS-limited), fully persistent

// scales: 1/RRD = 1/d^0.25 = 0.5 ;  1/(sqrt(2)*sqrt(d)) = 1/(4*sqrt(2))
#define S1 0.5f
#define S2 0.17677669529663687f

typedef float f4 __attribute__((ext_vector_type(4)));

__global__ __launch_bounds__(256)
void taylor_exp_kernel(const float* __restrict__ x, float* __restrict__ out, int ntiles)
{
    __shared__ float xs[ROWS_PER_TILE * INPUT_DIM];    // 1 KiB input tile
    __shared__ float os[FLOATS_PER_TILE];              // 17472 B output tile

    const int tid = threadIdx.x;
    const int row = tid >> 4;          // 0..15
    const int l   = tid & 15;          // 0..15
    const int base = row * COLS;
    float* o2 = &os[base + 17 + l];
    const f4* xsr = (const f4*)&xs[row * INPUT_DIM];

    for (int t = blockIdx.x; t < ntiles; t += NBLOCKS) {
        // stage input tile (1 KiB coalesced). Safe: previous iteration's LDS
        // reads are drained by the pre-barrier waitcnt below / prior barrier.
        xs[tid] = x[(long long)t * (ROWS_PER_TILE * INPUT_DIM) + tid];
        __syncthreads();

        // ---- compute phase: branch-free ----
        const float xl = xs[tid];
        const f4 r0 = xsr[0], r1 = xsr[1], r2 = xsr[2], r3 = xsr[3];

        os[base + 1 + l] = xl * S1;
        if (l == 0) os[base] = 1.0f;

        // os[base + 17 + j*16 + l] = (x[j]*x[l])*S2  (rounding order: absmax==0)
        o2[ 0 * 16] = (r0[0] * xl) * S2;
        o2[ 1 * 16] = (r0[1] * xl) * S2;
        o2[ 2 * 16] = (r0[2] * xl) * S2;
        o2[ 3 * 16] = (r0[3] * xl) * S2;
        o2[ 4 * 16] = (r1[0] * xl) * S2;
        o2[ 5 * 16] = (r1[1] * xl) * S2;
        o2[ 6 * 16] = (r1[2] * xl) * S2;
        o2[ 7 * 16] = (r1[3] * xl) * S2;
        o2[ 8 * 16] = (r2[0] * xl) * S2;
        o2[ 9 * 16] = (r2[1] * xl) * S2;
        o2[10 * 16] = (r2[2] * xl) * S2;
        o2[11 * 16] = (r2[3] * xl) * S2;
        o2[12 * 16] = (r3[0] * xl) * S2;
        o2[13 * 16] = (r3[1] * xl) * S2;
        o2[14 * 16] = (r3[2] * xl) * S2;
        o2[15 * 16] = (r3[3] * xl) * S2;

        __syncthreads();

        // ---- copy phase: LDS -> global, non-temporal streaming stores ----
        f4* __restrict__ out4 = (f4*)(out + (long long)t * FLOATS_PER_TILE);
        const f4* os4 = (const f4*)os;

        #pragma unroll
        for (int it = 0; it < 5; ++it) {
            const int v = tid + it * 256;        // 1092 = 4*256 + 68
            if (v < VEC4_PER_TILE) {
                __builtin_nontemporal_store(os4[v], &out4[v]);
            }
        }
        // next iteration's first __syncthreads() (with its implied LDS-op
        // drain) protects os against overwrite while copies are in flight
        __syncthreads();
    }
}

extern "C" void kernel_launch(void* const* d_in, const int* in_sizes, int n_in,
                              void* d_out, int out_size, void* d_ws, size_t ws_size,
                              hipStream_t stream)
{
    const float* x = (const float*)d_in[0];
    float* out = (float*)d_out;

    const int nrows  = in_sizes[0] / INPUT_DIM;        // 262144
    const int ntiles = nrows / ROWS_PER_TILE;          // 16384

    taylor_exp_kernel<<<NBLOCKS, 256, 0, stream>>>(x, out, ntiles);
}